// Round 8
// baseline (141.756 us; speedup 1.0000x reference)
//
#include <hip/hip_runtime.h>
#include <stdint.h>

// DecisionTree: out = sum_l p_l * (x @ W_l^T + b_l), p from bottom-layer sigmoids.
// Pair-folded + A-prescaled: ONE flat GEMM A[4096x9216] @ B[1024x9216]^T.
// tree_gemm6: 256x256 tile, BK=64. A in LDS (G4-swizzled, 2x32KB); B read
// DIRECTLY from L2-resident fragment-major wpf via coalesced dwordx4 ->
// cuts per-tile LDS traffic 260KB -> 160KB (round-7 showed DS+MFMA serialize).

#define M_TOK 4096
#define DDIM  1024
#define KFLAT 9216

typedef __bf16 bf16x8 __attribute__((ext_vector_type(8)));
typedef float  f32x4  __attribute__((ext_vector_type(4)));
typedef unsigned short u16x4 __attribute__((ext_vector_type(4)));
typedef unsigned short u16x8 __attribute__((ext_vector_type(8)));

#define GLB(p) ((const __attribute__((address_space(1))) void*)(p))
#define LDS(p) ((__attribute__((address_space(3))) void*)(p))

__device__ __forceinline__ unsigned short f2bf(float f) {
    union { float f; uint32_t u; } v; v.f = f;
    uint32_t u = v.u;
    return (unsigned short)((u + 0x7fffu + ((u >> 16) & 1u)) >> 16);  // RNE
}

__device__ __forceinline__ bf16x8 asbf(f32x4 v) {
    bf16x8 r; __builtin_memcpy(&r, &v, 16); return r;
}

template<int OFF>
__device__ __forceinline__ f32x4 dsr(uint32_t a) {
    f32x4 r;
    asm volatile("ds_read_b128 %0, %1 offset:%c2" : "=v"(r) : "v"(a), "i"(OFF));
    return r;
}

// ---- fused prep: blocks [0,1024) build W' + bias; [1024,2048) build xs + pmat ----
// newlay=1: fragment-major wpf [nt4][kt144][wn4][jh8][lane64][8bf16] (for gemm6)
// newlay=0: row-major wp [o][K]                                      (for gemm5/3)
__global__ __launch_bounds__(256) void prep_dec_kernel(
    const float* __restrict__ x, const float* __restrict__ dec_w,
    const float* __restrict__ dec_b, const float* __restrict__ lw,
    const float* __restrict__ lb, unsigned short* __restrict__ wp,
    float* __restrict__ bw, unsigned short* __restrict__ xs,
    float* __restrict__ pmat, int newlay)
{
    if (blockIdx.x < 1024) {
        int idx = blockIdx.x * 256 + threadIdx.x;     // (o, k4)
        int o  = idx >> 8;
        int k4 = (idx & 255) << 2;
        size_t src = (size_t)o * DDIM + k4;
        // dest for newlay: chunk coords from (o, K)
        const int nt = o >> 8, wn = (o >> 6) & 3, jj = (o >> 4) & 3, ra = o & 15;
        auto store4 = [&](int l, u16x4 d) {
            if (newlay) {
                int K    = l * DDIM + k4;
                int kt   = K >> 6;
                int half = (K >> 5) & 1;
                int g16  = (K >> 3) & 3;
                int e0   = K & 7;                     // 0 or 4
                size_t a = ((size_t)(nt * 144 + kt) * 4 + wn) * 4096
                         + (jj * 2 + half) * 512 + (g16 * 16 + ra) * 8 + e0;
                *(u16x4*)(wp + a) = d;
            } else {
                *(u16x4*)(wp + (size_t)o * KFLAT + l * DDIM + k4) = d;
            }
        };
        float4 acc = make_float4(0.f, 0.f, 0.f, 0.f);
#pragma unroll
        for (int j = 0; j < 8; ++j) {
            const float4 a = *(const float4*)(lw + (size_t)(2*j)   * DDIM*DDIM + src);
            const float4 b = *(const float4*)(lw + (size_t)(2*j+1) * DDIM*DDIM + src);
            u16x4 d;
            d[0] = f2bf(a.x - b.x); d[1] = f2bf(a.y - b.y);
            d[2] = f2bf(a.z - b.z); d[3] = f2bf(a.w - b.w);
            store4(j, d);
            acc.x += b.x; acc.y += b.y; acc.z += b.z; acc.w += b.w;
        }
        u16x4 s;
        s[0] = f2bf(acc.x); s[1] = f2bf(acc.y); s[2] = f2bf(acc.z); s[3] = f2bf(acc.w);
        store4(8, s);
        if ((idx & 255) == 0) {
            float sb = 0.f;
#pragma unroll
            for (int j = 0; j < 8; ++j) {
                float ba = lb[(2*j) * DDIM + o];
                float bb = lb[(2*j+1) * DDIM + o];
                bw[j * DDIM + o] = ba - bb;
                sb += bb;
            }
            bw[8 * DDIM + o] = sb;
        }
    } else {
        int m    = (blockIdx.x - 1024) * 4 + (threadIdx.x >> 6);
        int lane = threadIdx.x & 63;
        const float* xr = x + (size_t)m * DDIM + lane * 16;
        float xv[16];
        *(float4*)&xv[0]  = *(const float4*)(xr + 0);
        *(float4*)&xv[4]  = *(const float4*)(xr + 4);
        *(float4*)&xv[8]  = *(const float4*)(xr + 8);
        *(float4*)&xv[12] = *(const float4*)(xr + 12);
        float s[8];
#pragma unroll
        for (int j = 0; j < 8; ++j) {
            const float* wr = dec_w + (size_t)(7 + j) * DDIM + lane * 16;
            float a = 0.f;
#pragma unroll
            for (int i = 0; i < 16; i += 4) {
                float4 wv = *(const float4*)(wr + i);
                a = fmaf(xv[i], wv.x, fmaf(xv[i+1], wv.y, fmaf(xv[i+2], wv.z, fmaf(xv[i+3], wv.w, a))));
            }
            s[j] = a;
        }
#pragma unroll
        for (int j = 0; j < 8; ++j)
#pragma unroll
            for (int off = 32; off > 0; off >>= 1)
                s[j] += __shfl_xor(s[j], off);
        float p[8];
#pragma unroll
        for (int j = 0; j < 8; ++j)
            p[j] = 1.0f / (1.0f + expf(-(s[j] + dec_b[7 + j])));
        if (lane == 0) {
#pragma unroll
            for (int j = 0; j < 8; ++j)
                pmat[(size_t)m * 8 + j] = p[j];
        }
#pragma unroll
        for (int j = 0; j < 9; ++j) {
            float pj = (j < 8) ? p[j] : 1.0f;
            unsigned short* dst = xs + (size_t)m * KFLAT + j * DDIM + lane * 16;
#pragma unroll
            for (int c = 0; c < 2; ++c) {
                u16x8 o;
#pragma unroll
                for (int e = 0; e < 8; ++e) o[e] = f2bf(pj * xv[c * 8 + e]);
                *(u16x8*)(dst + c * 8) = o;
            }
        }
    }
}

// ---- wait/MFMA macros ----
#define WAITV0 asm volatile("s_waitcnt vmcnt(0)" ::: "memory")
#define BARR   __builtin_amdgcn_s_barrier()
#define LGKM0  do { asm volatile("s_waitcnt lgkmcnt(0)" ::: "memory"); \
                    __builtin_amdgcn_sched_barrier(0); } while(0)
#define LGKM4  do { asm volatile("s_waitcnt lgkmcnt(4)" ::: "memory"); \
                    __builtin_amdgcn_sched_barrier(0); } while(0)
#define WAITV4LG4 do { asm volatile("s_waitcnt vmcnt(4) lgkmcnt(4)" ::: "memory"); \
                       __builtin_amdgcn_sched_barrier(0); } while(0)
#define WAITV0LG4 do { asm volatile("s_waitcnt vmcnt(0) lgkmcnt(4)" ::: "memory"); \
                       __builtin_amdgcn_sched_barrier(0); } while(0)

#define MFMA_Q(q, SET) do { \
    __builtin_amdgcn_s_setprio(1); \
    _Pragma("unroll") \
    for (int mfl = 0; mfl < 2; ++mfl) { \
        _Pragma("unroll") \
        for (int j = 0; j < 4; ++j) { \
            acc[2*(q)+mfl][j] = __builtin_amdgcn_mfma_f32_16x16x32_bf16(asbf(SET[mfl][0]), asbf(bv[j][0]), acc[2*(q)+mfl][j], 0, 0, 0); \
            acc[2*(q)+mfl][j] = __builtin_amdgcn_mfma_f32_16x16x32_bf16(asbf(SET[mfl][1]), asbf(bv[j][1]), acc[2*(q)+mfl][j], 0, 0, 0); \
        } \
    } \
    __builtin_amdgcn_s_setprio(0); \
} while(0)

// ================= tree_gemm6: A-in-LDS, B-direct-from-L2 =================
// LDS: A0@0 A1@32K (64 KB). A row = 128B, G4 swizzle byte^=(row&7)<<4.
// B: wpf fragment-major, 8 coalesced dwordx4 per K-tile per wave, L2-resident.
#define RD_A(SET, q, boff) do { \
    SET[0][0] = dsr<(2*(q)+0)*2048>(bA0 + (boff)); \
    SET[0][1] = dsr<(2*(q)+0)*2048>(bA1 + (boff)); \
    SET[1][0] = dsr<(2*(q)+1)*2048>(bA0 + (boff)); \
    SET[1][1] = dsr<(2*(q)+1)*2048>(bA1 + (boff)); \
} while(0)

__global__ __launch_bounds__(512, 2) void tree_gemm6(
    const unsigned short* __restrict__ xs,   // [4096][9216] bf16
    const unsigned short* __restrict__ wpf,  // fragment-major B
    float* __restrict__ out, float* __restrict__ parts)
{
    extern __shared__ char smem[];
    const int tid  = threadIdx.x;
    const int lane = tid & 63;
    const int w    = tid >> 6;
    const int wm   = w >> 2, wn = w & 3;     // 2M x 4N waves
    const int ra   = lane & 15;
    const int g16  = lane >> 4;

    // mapping: xcd gets 2 (nt,g) combos; 16 mt-blocks per combo.
    const int flat = blockIdx.x;             // 0..255
    const int xcd  = flat & 7;
    const int idx  = flat >> 3;              // 0..31
    const int cc   = idx >> 4;               // 0..1
    const int mt   = idx & 15;
    const int code = xcd * 2 + cc;           // 0..15
    const int nt   = code >> 2;
    const int g    = code & 3;
    const int m0   = mt * 256, n0 = nt * 256;
    const int k0   = g * 2304;
    const int NT   = 36;

    uint32_t sbase = (uint32_t)(uintptr_t)(__attribute__((address_space(3))) char*)smem;
    const uint32_t colb0 = (uint32_t)((g16 ^ (ra & 7)) << 4);
    const uint32_t colb1 = colb0 ^ 64;
    const uint32_t bA0 = sbase + wm * 16384 + ra * 128 + colb0;
    const uint32_t bA1 = sbase + wm * 16384 + ra * 128 + colb1;

    const int kel = (((lane & 7) ^ (lane >> 3)) & 7) * 8;
    const int rA  = w * 8 + (lane >> 3);

    auto stageA = [&](int buf, int tt, int hh) {
        const unsigned short* s0 = xs + (size_t)(m0 + hh * 128 + rA) * KFLAT + (k0 + tt * 64 + kel);
        char* d0 = smem + buf * 32768 + hh * 16384 + w * 1024;
        __builtin_amdgcn_global_load_lds(GLB(s0), LDS(d0), 16, 0, 0);
        __builtin_amdgcn_global_load_lds(GLB(s0 + (size_t)64 * KFLAT), LDS(d0 + 8192), 16, 0, 0);
    };

    // B fragment source: [nt][kt][wn][jh][lane][8]; kt0 = g*36
    const unsigned short* bsrc = wpf
        + ((size_t)(nt * 144 + g * 36) * 4 + wn) * 4096 + lane * 8;

    f32x4 acc[8][4] = {};
    f32x4 avA[2][2], avB[2][2], bv[4][2];

    // prologue: stage A(0); drain; barrier.
    stageA(0, 0, 0); stageA(0, 0, 1);
    WAITV0;
    BARR;

    for (int t = 0; t < NT; ++t) {
        const bool on = (t + 1 < NT);
        // B loads for tile t (8 coalesced dwordx4, L2-hit)
#pragma unroll
        for (int j = 0; j < 4; ++j) {
            bv[j][0] = *(const f32x4*)(bsrc + (j * 2 + 0) * 512);
            bv[j][1] = *(const f32x4*)(bsrc + (j * 2 + 1) * 512);
        }
        // stage A(t+1) into buf (t+1)&1 (WAR covered by entry barrier)
        if (on) { stageA((t + 1) & 1, t + 1, 0); stageA((t + 1) & 1, t + 1, 1); }

        const uint32_t boff = (uint32_t)(t & 1) << 15;
        // quadrant-pipelined: q0+q1 issued, then counted-lgkm chain
        RD_A(avA, 0, boff);
        RD_A(avB, 1, boff);
        if (on) { WAITV4LG4; } else { WAITV0LG4; }   // B(t) done + q0 done
        MFMA_Q(0, avA);
        RD_A(avA, 2, boff);
        LGKM4;  MFMA_Q(1, avB);
        RD_A(avB, 3, boff);
        LGKM4;  MFMA_Q(2, avA);
        LGKM0;  MFMA_Q(3, avB);

        // boundary: A-stage(t+1) landed chip-wide before anyone reads it
        if (on) { WAITV0; BARR; }
        bsrc += 16384;                                // next kt
    }

    float* dst = (g == 0) ? out : parts + (size_t)(g - 1) * M_TOK * DDIM;
#pragma unroll
    for (int mf = 0; mf < 8; ++mf)
#pragma unroll
        for (int e = 0; e < 4; ++e) {
            int row = m0 + wm * 128 + mf * 16 + g16 * 4 + e;
#pragma unroll
            for (int j = 0; j < 4; ++j)
                dst[(size_t)row * DDIM + n0 + wn * 64 + j * 16 + ra] = acc[mf][j][e];
        }
}

// ---------------- reduce2: out = out + sum parts + bias(p . bw) ----------------
__global__ __launch_bounds__(256) void reduce2_kernel(
    float* __restrict__ out, const float* __restrict__ parts,
    const float* __restrict__ pmat, const float* __restrict__ bw, int np)
{
    size_t i = (size_t)blockIdx.x * 256 + threadIdx.x;
    int m   = (int)(i >> 8);
    int col = (int)(i & 255) * 4;
    float4 a = ((const float4*)out)[i];
    for (int p = 0; p < np; ++p) {
        float4 b = ((const float4*)(parts + (size_t)p * M_TOK * DDIM))[i];
        a.x += b.x; a.y += b.y; a.z += b.z; a.w += b.w;
    }
    float4 pa = *(const float4*)(pmat + (size_t)m * 8);
    float4 pb = *(const float4*)(pmat + (size_t)m * 8 + 4);
    float4 bias = *(const float4*)(bw + 8 * DDIM + col);
#pragma unroll
    for (int l = 0; l < 8; ++l) {
        float pl = (l < 4) ? ((const float*)&pa)[l] : ((const float*)&pb)[l - 4];
        float4 bl = *(const float4*)(bw + l * DDIM + col);
        bias.x = fmaf(pl, bl.x, bias.x); bias.y = fmaf(pl, bl.y, bias.y);
        bias.z = fmaf(pl, bl.z, bias.z); bias.w = fmaf(pl, bl.w, bias.w);
    }
    a.x += bias.x; a.y += bias.y; a.z += bias.z; a.w += bias.w;
    ((float4*)out)[i] = a;
}

// ================= fallback (round-7 proven): tree_gemm5 (old wp layout) =================
#define READ_A5(SET, q) do { \
    SET[0][0] = dsr<(2*(q)+0)*2048>(bA0); \
    SET[0][1] = dsr<(2*(q)+0)*2048>(bA1); \
    SET[1][0] = dsr<(2*(q)+1)*2048>(bA0); \
    SET[1][1] = dsr<(2*(q)+1)*2048>(bA1); \
} while(0)
#define READ_B5() do { \
    bv[0][0] = dsr<0*2048>(bB0); bv[0][1] = dsr<0*2048>(bB1); \
    bv[1][0] = dsr<1*2048>(bB0); bv[1][1] = dsr<1*2048>(bB1); \
    bv[2][0] = dsr<2*2048>(bB0); bv[2][1] = dsr<2*2048>(bB1); \
    bv[3][0] = dsr<3*2048>(bB0); bv[3][1] = dsr<3*2048>(bB1); \
} while(0)
#define WAITV8 asm volatile("s_waitcnt vmcnt(8)" ::: "memory")
#define WAITV4 asm volatile("s_waitcnt vmcnt(4)" ::: "memory")

__global__ __launch_bounds__(512, 2) void tree_gemm5(
    const unsigned short* __restrict__ xs, const unsigned short* __restrict__ wp,
    float* __restrict__ out, float* __restrict__ parts, int KG)
{
    extern __shared__ char smem[];
    const int tid  = threadIdx.x;
    const int lane = tid & 63;
    const int w    = tid >> 6;
    const int wm   = w >> 2, wn = w & 3;
    const int ra   = lane & 15;
    const int g16  = lane >> 4;
    const int bx  = blockIdx.x;
    const int xcd = bx & 7, ii = bx >> 3;
    const int nt  = xcd >> 1;
    const int mt  = (xcd & 1) * 8 + ii;
    const int m0  = mt * 256, n0 = nt * 256;
    const int g   = blockIdx.y;
    const int k0  = g * KG;
    const int NT  = KG >> 6;
    uint32_t sbase = (uint32_t)(uintptr_t)(__attribute__((address_space(3))) char*)smem;
    const uint32_t colb0 = (uint32_t)((g16 ^ (ra & 7)) << 4);
    const uint32_t colb1 = colb0 ^ 64;
    const uint32_t baseA0s = sbase + wm * 16384 + ra * 128 + colb0;
    const uint32_t baseA1s = sbase + wm * 16384 + ra * 128 + colb1;
    const uint32_t baseB0s = sbase + 65536 + wn * 8192 + ra * 128 + colb0;
    const uint32_t baseB1s = sbase + 65536 + wn * 8192 + ra * 128 + colb1;
    const int kel = (((lane & 7) ^ (lane >> 3)) & 7) * 8;
    const int rA  = w * 8 + (lane >> 3);
    auto stageA = [&](int buf, int tt, int hh) {
        const unsigned short* s0 = xs + (size_t)(m0 + hh * 128 + rA) * KFLAT + (k0 + tt * 64 + kel);
        char* d0 = smem + buf * 32768 + hh * 16384 + w * 1024;
        __builtin_amdgcn_global_load_lds(GLB(s0), LDS(d0), 16, 0, 0);
        __builtin_amdgcn_global_load_lds(GLB(s0 + (size_t)64 * KFLAT), LDS(d0 + 8192), 16, 0, 0);
    };
    auto stageB = [&](int buf, int tt, int hh) {
        const unsigned short* s0 = wp + (size_t)(n0 + hh * 128 + rA) * KFLAT + (k0 + tt * 64 + kel);
        char* d0 = smem + 65536 + buf * 32768 + hh * 16384 + w * 1024;
        __builtin_amdgcn_global_load_lds(GLB(s0), LDS(d0), 16, 0, 0);
        __builtin_amdgcn_global_load_lds(GLB(s0 + (size_t)64 * KFLAT), LDS(d0 + 8192), 16, 0, 0);
    };
    f32x4 acc[8][4] = {};
    f32x4 avA[2][2], avB[2][2], bv[4][2];
    stageA(0, 0, 0); stageA(0, 0, 1);
    stageB(0, 0, 0); stageB(0, 0, 1);
    stageA(1, 1, 0); stageA(1, 1, 1);
    stageB(1, 1, 0); stageB(1, 1, 1);
    WAITV8; BARR;
    int bt = 0, bt2 = 2;
    for (int t = 0; t < NT; ++t) {
        if (t) {
            if (t == NT - 1) { WAITV0; } else { WAITV4; }
            BARR;
        }
        if (t + 1 < NT) { stageA((t + 1) & 1, t + 1, 0); stageA((t + 1) & 1, t + 1, 1); }
        if (t + 2 < NT) { stageB(bt2, t + 2, 0); stageB(bt2, t + 2, 1); }
        const uint32_t aoff = (uint32_t)(t & 1) << 15;
        const uint32_t boffv = (uint32_t)bt << 15;
        const uint32_t bA0 = baseA0s + aoff, bA1 = baseA1s + aoff;
        const uint32_t bB0 = baseB0s + boffv, bB1 = baseB1s + boffv;
        READ_B5();
        READ_A5(avA, 0);
        READ_A5(avB, 1);
        LGKM4;  MFMA_Q(0, avA);
        READ_A5(avA, 2);
        LGKM4;  MFMA_Q(1, avB);
        READ_A5(avB, 3);
        LGKM4;  MFMA_Q(2, avA);
        LGKM0;  MFMA_Q(3, avB);
        bt  = (bt  == 2) ? 0 : bt  + 1;
        bt2 = (bt2 == 2) ? 0 : bt2 + 1;
    }
    float* dst = (g == 0) ? out : parts + (size_t)(g - 1) * M_TOK * DDIM;
#pragma unroll
    for (int mf = 0; mf < 8; ++mf)
#pragma unroll
        for (int e = 0; e < 4; ++e) {
            int row = m0 + wm * 128 + mf * 16 + g16 * 4 + e;
#pragma unroll
            for (int j = 0; j < 4; ++j)
                dst[(size_t)row * DDIM + n0 + wn * 64 + j * 16 + ra] = acc[mf][j][e];
        }
}

// ================= fallback #2 (round-3 proven): tree_gemm3 + reduce =================
__global__ __launch_bounds__(256, 4) void tree_gemm3(
    const unsigned short* __restrict__ xs, const unsigned short* __restrict__ wp,
    const float* __restrict__ bw, const float* __restrict__ pmat,
    float* __restrict__ out, float* __restrict__ parts, int KG)
{
    __shared__ __align__(16) unsigned short Asm[2][128 * 32];
    __shared__ __align__(16) unsigned short Bsm[2][128 * 32];
    const int tid  = threadIdx.x;
    const int lane = tid & 63;
    const int w    = tid >> 6;
    const int wm   = w >> 1, wn = w & 1;
    const int bx   = blockIdx.x;
    const int xcd  = bx & 7;
    const int ii   = bx >> 3;
    const int mt   = xcd * 4 + (ii >> 3);
    const int nt   = ii & 7;
    const int m0   = mt * 128, n0 = nt * 128;
    const int g    = blockIdx.y;
    const int k0   = g * KG;
    const int ra   = lane & 15;
    const int kb   = (lane >> 4) * 8;
    f32x4 acc[4][4] = {};
    auto stage = [&](int buf, int t) {
#pragma unroll
        for (int c = 0; c < 2; ++c) {
            int row = w * 32 + c * 16 + (lane >> 2);
            int ke  = k0 + t * 32 + (lane & 3) * 8;
            const unsigned short* ga = xs + (size_t)(m0 + row) * KFLAT + ke;
            __builtin_amdgcn_global_load_lds(GLB(ga), LDS(&Asm[buf][w * 1024 + c * 512]), 16, 0, 0);
            const unsigned short* gb = wp + (size_t)(n0 + row) * KFLAT + ke;
            __builtin_amdgcn_global_load_lds(GLB(gb), LDS(&Bsm[buf][w * 1024 + c * 512]), 16, 0, 0);
        }
    };
    const int TOT = KG >> 5;
    stage(0, 0);
    __syncthreads();
    int cur = 0;
    for (int t = 0; t < TOT; ++t) {
        if (t + 1 < TOT) stage(cur ^ 1, t + 1);
        bf16x8 av2[4], bv2[4];
#pragma unroll
        for (int i2 = 0; i2 < 4; ++i2)
            av2[i2] = *(const bf16x8*)&Asm[cur][(wm * 64 + i2 * 16 + ra) * 32 + kb];
#pragma unroll
        for (int j = 0; j < 4; ++j)
            bv2[j] = *(const bf16x8*)&Bsm[cur][(wn * 64 + j * 16 + ra) * 32 + kb];
#pragma unroll
        for (int i2 = 0; i2 < 4; ++i2)
#pragma unroll
            for (int j = 0; j < 4; ++j)
                acc[i2][j] = __builtin_amdgcn_mfma_f32_16x16x32_bf16(av2[i2], bv2[j], acc[i2][j], 0, 0, 0);
        __syncthreads();
        cur ^= 1;
    }
    float* bsm = (float*)&Asm[0][0];
    if (g == 0) {
        for (int idx = tid; idx < 9 * 128; idx += 256)
            bsm[idx] = bw[(idx >> 7) * DDIM + n0 + (idx & 127)];
    }
    __syncthreads();
    float* dst = (g == 0) ? out : parts + (size_t)(g - 1) * M_TOK * DDIM;
#pragma unroll
    for (int i2 = 0; i2 < 4; ++i2)
#pragma unroll
        for (int r = 0; r < 4; ++r) {
            int row = m0 + wm * 64 + i2 * 16 + (lane >> 4) * 4 + r;
            float4 pa, pb;
            if (g == 0) {
                pa = *(const float4*)(pmat + (size_t)row * 8);
                pb = *(const float4*)(pmat + (size_t)row * 8 + 4);
            }
#pragma unroll
            for (int j = 0; j < 4; ++j) {
                int cl = wn * 64 + j * 16 + ra;
                float v = acc[i2][j][r];
                if (g == 0) {
                    v += pa.x * bsm[0 * 128 + cl] + pa.y * bsm[1 * 128 + cl]
                       + pa.z * bsm[2 * 128 + cl] + pa.w * bsm[3 * 128 + cl]
                       + pb.x * bsm[4 * 128 + cl] + pb.y * bsm[5 * 128 + cl]
                       + pb.z * bsm[6 * 128 + cl] + pb.w * bsm[7 * 128 + cl]
                       + bsm[8 * 128 + cl];
                }
                dst[(size_t)row * DDIM + n0 + cl] = v;
            }
        }
}

__global__ __launch_bounds__(256) void reduce_kernel(
    float* __restrict__ out, const float* __restrict__ parts, int np)
{
    size_t i = (size_t)blockIdx.x * 256 + threadIdx.x;
    float4 a = ((const float4*)out)[i];
    for (int p = 0; p < np; ++p) {
        float4 b = ((const float4*)(parts + (size_t)p * M_TOK * DDIM))[i];
        a.x += b.x; a.y += b.y; a.z += b.z; a.w += b.w;
    }
    ((float4*)out)[i] = a;
}

extern "C" void kernel_launch(void* const* d_in, const int* in_sizes, int n_in,
                              void* d_out, int out_size, void* d_ws, size_t ws_size,
                              hipStream_t stream) {
    (void)in_sizes; (void)n_in; (void)out_size;
    const float* x     = (const float*)d_in[0];
    const float* dec_w = (const float*)d_in[1];
    const float* dec_b = (const float*)d_in[2];
    const float* lw    = (const float*)d_in[3];
    const float* lb    = (const float*)d_in[4];
    float* out = (float*)d_out;
    uint8_t* w8 = (uint8_t*)d_ws;

    unsigned short* xs   = (unsigned short*)(w8);
    unsigned short* wp   = (unsigned short*)(w8 + 75497472);   // 18 MiB (either layout)
    float*          bw   = (float*)(w8 + 94371840);
    float*          pmat = (float*)(w8 + 94408704);
    float*          parts= (float*)(w8 + 94539776);
    const size_t NEED3 = 94539776 + 2ull * 16777216;
    const size_t NEED4 = 94539776 + 3ull * 16777216;

    int ks = (ws_size >= NEED4) ? 4 : (ws_size >= NEED3) ? 3 : 0;
    if (!ks) return;

    // pick GEMM path FIRST (prep layout depends on it)
    bool use6 = false;
    if (ks == 4) {
        hipError_t e6 = hipFuncSetAttribute(
            reinterpret_cast<const void*>(tree_gemm6),
            hipFuncAttributeMaxDynamicSharedMemorySize, 65536);
        use6 = (e6 == hipSuccess);
    }

    prep_dec_kernel<<<2048, 256, 0, stream>>>(x, dec_w, dec_b, lw, lb, wp, bw, xs, pmat,
                                              use6 ? 1 : 0);

    if (use6) {
        tree_gemm6<<<256, 512, 65536, stream>>>(xs, wp, out, parts);
        reduce2_kernel<<<4096, 256, 0, stream>>>(out, parts, pmat, bw, 3);
        return;
    }

    hipError_t e5 = hipFuncSetAttribute(
        reinterpret_cast<const void*>(tree_gemm5),
        hipFuncAttributeMaxDynamicSharedMemorySize, 163840);
    if (e5 == hipSuccess) {
        tree_gemm5<<<dim3(64, ks), 512, 163840, stream>>>(xs, wp, out, parts, KFLAT / ks);
        reduce2_kernel<<<4096, 256, 0, stream>>>(out, parts, pmat, bw, ks - 1);
    } else {
        tree_gemm3<<<dim3(256, ks), 256, 0, stream>>>(xs, wp, bw, pmat, out, parts, KFLAT / ks);
        reduce_kernel<<<4096, 256, 0, stream>>>(out, parts, ks - 1);
    }
}

// Round 9
// 139.071 us; speedup vs baseline: 1.0193x; 1.0193x over previous
//
#include <hip/hip_runtime.h>
#include <stdint.h>

// DecisionTree: out = sum_l p_l * (x @ W_l^T + b_l), p from bottom-layer sigmoids.
// Pair-folded + A-prescaled: ONE flat GEMM A[4096x9216] @ B[1024x9216]^T.
// tree_gemm7: 128x256 tile, BK=32, 512 blocks => 2 blocks/CU, 16 waves/CU
// (r6-r8 showed MfmaUtil pinned at ~37% with 1 block/CU regardless of schedule;
// the missing ingredient is an independent co-tenant block to anti-phase pipes).

#define M_TOK 4096
#define DDIM  1024
#define KFLAT 9216

typedef __bf16 bf16x8 __attribute__((ext_vector_type(8)));
typedef float  f32x4  __attribute__((ext_vector_type(4)));
typedef unsigned short u16x4 __attribute__((ext_vector_type(4)));
typedef unsigned short u16x8 __attribute__((ext_vector_type(8)));

#define GLB(p) ((const __attribute__((address_space(1))) void*)(p))
#define LDS(p) ((__attribute__((address_space(3))) void*)(p))

__device__ __forceinline__ unsigned short f2bf(float f) {
    union { float f; uint32_t u; } v; v.f = f;
    uint32_t u = v.u;
    return (unsigned short)((u + 0x7fffu + ((u >> 16) & 1u)) >> 16);  // RNE
}

__device__ __forceinline__ bf16x8 asbf(f32x4 v) {
    bf16x8 r; __builtin_memcpy(&r, &v, 16); return r;
}

template<int OFF>
__device__ __forceinline__ f32x4 dsr(uint32_t a) {
    f32x4 r;
    asm volatile("ds_read_b128 %0, %1 offset:%c2" : "=v"(r) : "v"(a), "i"(OFF));
    return r;
}

// ---- fused prep: blocks [0,1024) build W'(flat-K) + bias; [1024,2048) build xs + pmat ----
__global__ __launch_bounds__(256) void prep_dec_kernel(
    const float* __restrict__ x, const float* __restrict__ dec_w,
    const float* __restrict__ dec_b, const float* __restrict__ lw,
    const float* __restrict__ lb, unsigned short* __restrict__ wp,
    float* __restrict__ bw, unsigned short* __restrict__ xs,
    float* __restrict__ pmat)
{
    if (blockIdx.x < 1024) {
        int idx = blockIdx.x * 256 + threadIdx.x;     // (o, k4)
        int o  = idx >> 8;
        int k4 = (idx & 255) << 2;
        size_t src = (size_t)o * DDIM + k4;
        size_t dstb = (size_t)o * KFLAT + k4;
        float4 acc = make_float4(0.f, 0.f, 0.f, 0.f);
#pragma unroll
        for (int j = 0; j < 8; ++j) {
            const float4 a = *(const float4*)(lw + (size_t)(2*j)   * DDIM*DDIM + src);
            const float4 b = *(const float4*)(lw + (size_t)(2*j+1) * DDIM*DDIM + src);
            u16x4 d;
            d[0] = f2bf(a.x - b.x); d[1] = f2bf(a.y - b.y);
            d[2] = f2bf(a.z - b.z); d[3] = f2bf(a.w - b.w);
            *(u16x4*)(wp + dstb + (size_t)j * DDIM) = d;
            acc.x += b.x; acc.y += b.y; acc.z += b.z; acc.w += b.w;
        }
        u16x4 s;
        s[0] = f2bf(acc.x); s[1] = f2bf(acc.y); s[2] = f2bf(acc.z); s[3] = f2bf(acc.w);
        *(u16x4*)(wp + dstb + (size_t)8 * DDIM) = s;
        if ((idx & 255) == 0) {
            float sb = 0.f;
#pragma unroll
            for (int j = 0; j < 8; ++j) {
                float ba = lb[(2*j) * DDIM + o];
                float bb = lb[(2*j+1) * DDIM + o];
                bw[j * DDIM + o] = ba - bb;
                sb += bb;
            }
            bw[8 * DDIM + o] = sb;
        }
    } else {
        int m    = (blockIdx.x - 1024) * 4 + (threadIdx.x >> 6);
        int lane = threadIdx.x & 63;
        const float* xr = x + (size_t)m * DDIM + lane * 16;
        float xv[16];
        *(float4*)&xv[0]  = *(const float4*)(xr + 0);
        *(float4*)&xv[4]  = *(const float4*)(xr + 4);
        *(float4*)&xv[8]  = *(const float4*)(xr + 8);
        *(float4*)&xv[12] = *(const float4*)(xr + 12);
        float s[8];
#pragma unroll
        for (int j = 0; j < 8; ++j) {
            const float* wr = dec_w + (size_t)(7 + j) * DDIM + lane * 16;
            float a = 0.f;
#pragma unroll
            for (int i = 0; i < 16; i += 4) {
                float4 wv = *(const float4*)(wr + i);
                a = fmaf(xv[i], wv.x, fmaf(xv[i+1], wv.y, fmaf(xv[i+2], wv.z, fmaf(xv[i+3], wv.w, a))));
            }
            s[j] = a;
        }
#pragma unroll
        for (int j = 0; j < 8; ++j)
#pragma unroll
            for (int off = 32; off > 0; off >>= 1)
                s[j] += __shfl_xor(s[j], off);
        float p[8];
#pragma unroll
        for (int j = 0; j < 8; ++j)
            p[j] = 1.0f / (1.0f + expf(-(s[j] + dec_b[7 + j])));
        if (lane == 0) {
#pragma unroll
            for (int j = 0; j < 8; ++j)
                pmat[(size_t)m * 8 + j] = p[j];
        }
#pragma unroll
        for (int j = 0; j < 9; ++j) {
            float pj = (j < 8) ? p[j] : 1.0f;
            unsigned short* dst = xs + (size_t)m * KFLAT + j * DDIM + lane * 16;
#pragma unroll
            for (int c = 0; c < 2; ++c) {
                u16x8 o;
#pragma unroll
                for (int e = 0; e < 8; ++e) o[e] = f2bf(pj * xv[c * 8 + e]);
                *(u16x8*)(dst + c * 8) = o;
            }
        }
    }
}

// ---- wait macros ----
#define WAITV0 asm volatile("s_waitcnt vmcnt(0)" ::: "memory")
#define WAITV4 asm volatile("s_waitcnt vmcnt(4)" ::: "memory")
#define WAITV8 asm volatile("s_waitcnt vmcnt(8)" ::: "memory")
#define BARR   __builtin_amdgcn_s_barrier()
#define LGKM0  do { asm volatile("s_waitcnt lgkmcnt(0)" ::: "memory"); \
                    __builtin_amdgcn_sched_barrier(0); } while(0)
#define LGKM2  do { asm volatile("s_waitcnt lgkmcnt(2)" ::: "memory"); \
                    __builtin_amdgcn_sched_barrier(0); } while(0)
#define LGKM4  do { asm volatile("s_waitcnt lgkmcnt(4)" ::: "memory"); \
                    __builtin_amdgcn_sched_barrier(0); } while(0)

// ================= tree_gemm7: 128x256 tile, BK=32, 2 blocks/CU =================
// LDS 48KB: A0@0 A1@8K (128x32 bf16 each) | B0@16K B1@32K (256x32 each).
// Row = 64B. Swizzle: 16B-slot ^= (row>>1)&3 (bank-uniform for b128 reads,
// derivation in r9 notes). Linear gload_lds dest + inverse-XOR global src.
__global__ __launch_bounds__(512, 4) void tree_gemm7(
    const unsigned short* __restrict__ xs,   // [4096][9216] bf16
    const unsigned short* __restrict__ wp,   // [1024][9216] bf16
    float* __restrict__ out, float* __restrict__ parts)
{
    extern __shared__ char smem[];
    const int tid  = threadIdx.x;
    const int lane = tid & 63;
    const int w    = tid >> 6;               // 0..7
    const int wm   = w >> 2, wn = w & 3;     // 2M x 4N waves, wave tile 64x64
    const int ra   = lane & 15;
    const int g16  = lane >> 4;

    // 512 blocks: xcd = bx&7 owns 2 (nt,g) combos x 32 mt (B panel 2.36MB L2-resident)
    const int bx   = blockIdx.x;
    const int xcd  = bx & 7;
    const int rest = bx >> 3;                // 0..63
    const int cc   = rest >> 5;              // 0..1
    const int mt   = rest & 31;              // 0..31
    const int code = xcd * 2 + cc;           // 0..15
    const int nt   = code >> 2;              // 0..3
    const int g    = code & 3;               // 0..3
    const int m0   = mt * 128, n0 = nt * 256;
    const int k0   = g * 2304;
    const int NT   = 72;                     // 2304 / 32

    uint32_t sbase = (uint32_t)(uintptr_t)(__attribute__((address_space(3))) char*)smem;
    const uint32_t colb = (uint32_t)((g16 ^ ((ra >> 1) & 3)) << 4);
    const uint32_t bAr = sbase + (uint32_t)(wm * 64 + ra) * 64 + colb;          // +m*1024, buf +8192
    const uint32_t bBr = sbase + 16384 + (uint32_t)(wn * 64 + ra) * 64 + colb;  // +j*1024, buf +16384

    // staging: thread tid -> row tid>>2, physical 16B-slot tid&3;
    // logical slot = phys ^ ((row>>1)&3) = (tid&3) ^ ((tid>>3)&3)
    const int rowS = tid >> 2;               // 0..127
    const int kel  = (((tid & 3) ^ ((tid >> 3) & 3)) & 3) * 8;

    auto stageA = [&](int buf, int tt) {
        const unsigned short* s0 = xs + (size_t)(m0 + rowS) * KFLAT + (k0 + tt * 32 + kel);
        char* d0 = smem + buf * 8192 + w * 1024;
        __builtin_amdgcn_global_load_lds(GLB(s0), LDS(d0), 16, 0, 0);
    };
    auto stageB = [&](int buf, int tt) {
        const unsigned short* s0 = wp + (size_t)(n0 + rowS) * KFLAT + (k0 + tt * 32 + kel);
        char* d0 = smem + 16384 + buf * 16384 + w * 1024;
        __builtin_amdgcn_global_load_lds(GLB(s0), LDS(d0), 16, 0, 0);
        __builtin_amdgcn_global_load_lds(GLB(s0 + (size_t)128 * KFLAT), LDS(d0 + 8192), 16, 0, 0);
    };

    f32x4 acc[4][4] = {};
    f32x4 av[4], bv[4];

    stageA(0, 0); stageB(0, 0);              // 3 loads
    WAITV0;
    BARR;

    for (int t = 0; t < NT; ++t) {
        const bool on = (t + 1 < NT);
        // stage next tile (3 loads); full tile of compute hides L2/HBM latency
        if (on) { stageA((t + 1) & 1, t + 1); stageB((t + 1) & 1, t + 1); }

        const uint32_t bA = bAr + ((uint32_t)(t & 1) << 13);
        const uint32_t bB = bBr + ((uint32_t)(t & 1) << 14);
        // issue order: av0,av1,bv0,bv1 | bv2,bv3 | av2,av3
        av[0] = dsr<0>(bA);    av[1] = dsr<1024>(bA);
        bv[0] = dsr<0>(bB);    bv[1] = dsr<1024>(bB);
        bv[2] = dsr<2048>(bB); bv[3] = dsr<3072>(bB);
        av[2] = dsr<2048>(bA); av[3] = dsr<3072>(bA);

        LGKM4;                                // av0,av1,bv0,bv1 landed
        __builtin_amdgcn_s_setprio(1);
#pragma unroll
        for (int m = 0; m < 2; ++m)
#pragma unroll
            for (int j = 0; j < 2; ++j)
                acc[m][j] = __builtin_amdgcn_mfma_f32_16x16x32_bf16(asbf(av[m]), asbf(bv[j]), acc[m][j], 0, 0, 0);
        __builtin_amdgcn_s_setprio(0);
        LGKM2;                                // bv2,bv3 landed
        __builtin_amdgcn_s_setprio(1);
#pragma unroll
        for (int m = 0; m < 2; ++m)
#pragma unroll
            for (int j = 2; j < 4; ++j)
                acc[m][j] = __builtin_amdgcn_mfma_f32_16x16x32_bf16(asbf(av[m]), asbf(bv[j]), acc[m][j], 0, 0, 0);
        __builtin_amdgcn_s_setprio(0);
        LGKM0;                                // av2,av3 landed
        __builtin_amdgcn_s_setprio(1);
#pragma unroll
        for (int m = 2; m < 4; ++m)
#pragma unroll
            for (int j = 0; j < 4; ++j)
                acc[m][j] = __builtin_amdgcn_mfma_f32_16x16x32_bf16(asbf(av[m]), asbf(bv[j]), acc[m][j], 0, 0, 0);
        __builtin_amdgcn_s_setprio(0);

        // boundary: stage(t+1) landed chip-wide before anyone reads it next tile
        WAITV0;
        BARR;
    }

    float* dst = (g == 0) ? out : parts + (size_t)(g - 1) * M_TOK * DDIM;
#pragma unroll
    for (int m = 0; m < 4; ++m)
#pragma unroll
        for (int e = 0; e < 4; ++e) {
            int row = m0 + wm * 64 + m * 16 + g16 * 4 + e;
#pragma unroll
            for (int j = 0; j < 4; ++j)
                dst[(size_t)row * DDIM + n0 + wn * 64 + j * 16 + ra] = acc[m][j][e];
        }
}

// ---------------- reduce2: out = out + sum parts + bias(p . bw) ----------------
__global__ __launch_bounds__(256) void reduce2_kernel(
    float* __restrict__ out, const float* __restrict__ parts,
    const float* __restrict__ pmat, const float* __restrict__ bw, int np)
{
    size_t i = (size_t)blockIdx.x * 256 + threadIdx.x;
    int m   = (int)(i >> 8);
    int col = (int)(i & 255) * 4;
    float4 a = ((const float4*)out)[i];
    for (int p = 0; p < np; ++p) {
        float4 b = ((const float4*)(parts + (size_t)p * M_TOK * DDIM))[i];
        a.x += b.x; a.y += b.y; a.z += b.z; a.w += b.w;
    }
    float4 pa = *(const float4*)(pmat + (size_t)m * 8);
    float4 pb = *(const float4*)(pmat + (size_t)m * 8 + 4);
    float4 bias = *(const float4*)(bw + 8 * DDIM + col);
#pragma unroll
    for (int l = 0; l < 8; ++l) {
        float pl = (l < 4) ? ((const float*)&pa)[l] : ((const float*)&pb)[l - 4];
        float4 bl = *(const float4*)(bw + l * DDIM + col);
        bias.x = fmaf(pl, bl.x, bias.x); bias.y = fmaf(pl, bl.y, bias.y);
        bias.z = fmaf(pl, bl.z, bias.z); bias.w = fmaf(pl, bl.w, bias.w);
    }
    a.x += bias.x; a.y += bias.y; a.z += bias.z; a.w += bias.w;
    ((float4*)out)[i] = a;
}

// ================= fallback #1 (round-7 proven): tree_gemm5 =================
#define MFMA_Q(q, SET) do { \
    __builtin_amdgcn_s_setprio(1); \
    _Pragma("unroll") \
    for (int mfl = 0; mfl < 2; ++mfl) { \
        _Pragma("unroll") \
        for (int j = 0; j < 4; ++j) { \
            acc[2*(q)+mfl][j] = __builtin_amdgcn_mfma_f32_16x16x32_bf16(asbf(SET[mfl][0]), asbf(bv[j][0]), acc[2*(q)+mfl][j], 0, 0, 0); \
            acc[2*(q)+mfl][j] = __builtin_amdgcn_mfma_f32_16x16x32_bf16(asbf(SET[mfl][1]), asbf(bv[j][1]), acc[2*(q)+mfl][j], 0, 0, 0); \
        } \
    } \
    __builtin_amdgcn_s_setprio(0); \
} while(0)
#define READ_A5(SET, q) do { \
    SET[0][0] = dsr<(2*(q)+0)*2048>(bA0); \
    SET[0][1] = dsr<(2*(q)+0)*2048>(bA1); \
    SET[1][0] = dsr<(2*(q)+1)*2048>(bA0); \
    SET[1][1] = dsr<(2*(q)+1)*2048>(bA1); \
} while(0)
#define READ_B5() do { \
    bv[0][0] = dsr<0*2048>(bB0); bv[0][1] = dsr<0*2048>(bB1); \
    bv[1][0] = dsr<1*2048>(bB0); bv[1][1] = dsr<1*2048>(bB1); \
    bv[2][0] = dsr<2*2048>(bB0); bv[2][1] = dsr<2*2048>(bB1); \
    bv[3][0] = dsr<3*2048>(bB0); bv[3][1] = dsr<3*2048>(bB1); \
} while(0)

__global__ __launch_bounds__(512, 2) void tree_gemm5(
    const unsigned short* __restrict__ xs, const unsigned short* __restrict__ wp,
    float* __restrict__ out, float* __restrict__ parts, int KG)
{
    extern __shared__ char smem[];
    const int tid  = threadIdx.x;
    const int lane = tid & 63;
    const int w    = tid >> 6;
    const int wm   = w >> 2, wn = w & 3;
    const int ra   = lane & 15;
    const int g16  = lane >> 4;
    const int bx  = blockIdx.x;
    const int xcd = bx & 7, ii = bx >> 3;
    const int nt  = xcd >> 1;
    const int mt  = (xcd & 1) * 8 + ii;
    const int m0  = mt * 256, n0 = nt * 256;
    const int g   = blockIdx.y;
    const int k0  = g * KG;
    const int NT  = KG >> 6;
    uint32_t sbase = (uint32_t)(uintptr_t)(__attribute__((address_space(3))) char*)smem;
    const uint32_t colb0 = (uint32_t)((g16 ^ (ra & 7)) << 4);
    const uint32_t colb1 = colb0 ^ 64;
    const uint32_t baseA0s = sbase + wm * 16384 + ra * 128 + colb0;
    const uint32_t baseA1s = sbase + wm * 16384 + ra * 128 + colb1;
    const uint32_t baseB0s = sbase + 65536 + wn * 8192 + ra * 128 + colb0;
    const uint32_t baseB1s = sbase + 65536 + wn * 8192 + ra * 128 + colb1;
    const int kel = (((lane & 7) ^ (lane >> 3)) & 7) * 8;
    const int rA  = w * 8 + (lane >> 3);
    auto stageA = [&](int buf, int tt, int hh) {
        const unsigned short* s0 = xs + (size_t)(m0 + hh * 128 + rA) * KFLAT + (k0 + tt * 64 + kel);
        char* d0 = smem + buf * 32768 + hh * 16384 + w * 1024;
        __builtin_amdgcn_global_load_lds(GLB(s0), LDS(d0), 16, 0, 0);
        __builtin_amdgcn_global_load_lds(GLB(s0 + (size_t)64 * KFLAT), LDS(d0 + 8192), 16, 0, 0);
    };
    auto stageB = [&](int buf, int tt, int hh) {
        const unsigned short* s0 = wp + (size_t)(n0 + hh * 128 + rA) * KFLAT + (k0 + tt * 64 + kel);
        char* d0 = smem + 65536 + buf * 32768 + hh * 16384 + w * 1024;
        __builtin_amdgcn_global_load_lds(GLB(s0), LDS(d0), 16, 0, 0);
        __builtin_amdgcn_global_load_lds(GLB(s0 + (size_t)64 * KFLAT), LDS(d0 + 8192), 16, 0, 0);
    };
    f32x4 acc[8][4] = {};
    f32x4 avA[2][2], avB[2][2], bv[4][2];
    stageA(0, 0, 0); stageA(0, 0, 1);
    stageB(0, 0, 0); stageB(0, 0, 1);
    stageA(1, 1, 0); stageA(1, 1, 1);
    stageB(1, 1, 0); stageB(1, 1, 1);
    WAITV8; BARR;
    int bt = 0, bt2 = 2;
    for (int t = 0; t < NT; ++t) {
        if (t) {
            if (t == NT - 1) { WAITV0; } else { WAITV4; }
            BARR;
        }
        if (t + 1 < NT) { stageA((t + 1) & 1, t + 1, 0); stageA((t + 1) & 1, t + 1, 1); }
        if (t + 2 < NT) { stageB(bt2, t + 2, 0); stageB(bt2, t + 2, 1); }
        const uint32_t aoff = (uint32_t)(t & 1) << 15;
        const uint32_t boffv = (uint32_t)bt << 15;
        const uint32_t bA0 = baseA0s + aoff, bA1 = baseA1s + aoff;
        const uint32_t bB0 = baseB0s + boffv, bB1 = baseB1s + boffv;
        READ_B5();
        READ_A5(avA, 0);
        READ_A5(avB, 1);
        LGKM4;  MFMA_Q(0, avA);
        READ_A5(avA, 2);
        LGKM4;  MFMA_Q(1, avB);
        READ_A5(avB, 3);
        LGKM4;  MFMA_Q(2, avA);
        LGKM0;  MFMA_Q(3, avB);
        bt  = (bt  == 2) ? 0 : bt  + 1;
        bt2 = (bt2 == 2) ? 0 : bt2 + 1;
    }
    float* dst = (g == 0) ? out : parts + (size_t)(g - 1) * M_TOK * DDIM;
#pragma unroll
    for (int mf = 0; mf < 8; ++mf)
#pragma unroll
        for (int e = 0; e < 4; ++e) {
            int row = m0 + wm * 128 + mf * 16 + g16 * 4 + e;
#pragma unroll
            for (int j = 0; j < 4; ++j)
                dst[(size_t)row * DDIM + n0 + wn * 64 + j * 16 + ra] = acc[mf][j][e];
        }
}

// ================= fallback #2 (round-3 proven): tree_gemm3 + reduce =================
__global__ __launch_bounds__(256, 4) void tree_gemm3(
    const unsigned short* __restrict__ xs, const unsigned short* __restrict__ wp,
    const float* __restrict__ bw, const float* __restrict__ pmat,
    float* __restrict__ out, float* __restrict__ parts, int KG)
{
    __shared__ __align__(16) unsigned short Asm[2][128 * 32];
    __shared__ __align__(16) unsigned short Bsm[2][128 * 32];
    const int tid  = threadIdx.x;
    const int lane = tid & 63;
    const int w    = tid >> 6;
    const int wm   = w >> 1, wn = w & 1;
    const int bx   = blockIdx.x;
    const int xcd  = bx & 7;
    const int ii   = bx >> 3;
    const int mt   = xcd * 4 + (ii >> 3);
    const int nt   = ii & 7;
    const int m0   = mt * 128, n0 = nt * 128;
    const int g    = blockIdx.y;
    const int k0   = g * KG;
    const int ra   = lane & 15;
    const int kb   = (lane >> 4) * 8;
    f32x4 acc[4][4] = {};
    auto stage = [&](int buf, int t) {
#pragma unroll
        for (int c = 0; c < 2; ++c) {
            int row = w * 32 + c * 16 + (lane >> 2);
            int ke  = k0 + t * 32 + (lane & 3) * 8;
            const unsigned short* ga = xs + (size_t)(m0 + row) * KFLAT + ke;
            __builtin_amdgcn_global_load_lds(GLB(ga), LDS(&Asm[buf][w * 1024 + c * 512]), 16, 0, 0);
            const unsigned short* gb = wp + (size_t)(n0 + row) * KFLAT + ke;
            __builtin_amdgcn_global_load_lds(GLB(gb), LDS(&Bsm[buf][w * 1024 + c * 512]), 16, 0, 0);
        }
    };
    const int TOT = KG >> 5;
    stage(0, 0);
    __syncthreads();
    int cur = 0;
    for (int t = 0; t < TOT; ++t) {
        if (t + 1 < TOT) stage(cur ^ 1, t + 1);
        bf16x8 av2[4], bv2[4];
#pragma unroll
        for (int i2 = 0; i2 < 4; ++i2)
            av2[i2] = *(const bf16x8*)&Asm[cur][(wm * 64 + i2 * 16 + ra) * 32 + kb];
#pragma unroll
        for (int j = 0; j < 4; ++j)
            bv2[j] = *(const bf16x8*)&Bsm[cur][(wn * 64 + j * 16 + ra) * 32 + kb];
#pragma unroll
        for (int i2 = 0; i2 < 4; ++i2)
#pragma unroll
            for (int j = 0; j < 4; ++j)
                acc[i2][j] = __builtin_amdgcn_mfma_f32_16x16x32_bf16(av2[i2], bv2[j], acc[i2][j], 0, 0, 0);
        __syncthreads();
        cur ^= 1;
    }
    float* bsm = (float*)&Asm[0][0];
    if (g == 0) {
        for (int idx = tid; idx < 9 * 128; idx += 256)
            bsm[idx] = bw[(idx >> 7) * DDIM + n0 + (idx & 127)];
    }
    __syncthreads();
    float* dst = (g == 0) ? out : parts + (size_t)(g - 1) * M_TOK * DDIM;
#pragma unroll
    for (int i2 = 0; i2 < 4; ++i2)
#pragma unroll
        for (int r = 0; r < 4; ++r) {
            int row = m0 + wm * 64 + i2 * 16 + (lane >> 4) * 4 + r;
            float4 pa, pb;
            if (g == 0) {
                pa = *(const float4*)(pmat + (size_t)row * 8);
                pb = *(const float4*)(pmat + (size_t)row * 8 + 4);
            }
#pragma unroll
            for (int j = 0; j < 4; ++j) {
                int cl = wn * 64 + j * 16 + ra;
                float v = acc[i2][j][r];
                if (g == 0) {
                    v += pa.x * bsm[0 * 128 + cl] + pa.y * bsm[1 * 128 + cl]
                       + pa.z * bsm[2 * 128 + cl] + pa.w * bsm[3 * 128 + cl]
                       + pb.x * bsm[4 * 128 + cl] + pb.y * bsm[5 * 128 + cl]
                       + pb.z * bsm[6 * 128 + cl] + pb.w * bsm[7 * 128 + cl]
                       + bsm[8 * 128 + cl];
                }
                dst[(size_t)row * DDIM + n0 + cl] = v;
            }
        }
}

__global__ __launch_bounds__(256) void reduce_kernel(
    float* __restrict__ out, const float* __restrict__ parts, int np)
{
    size_t i = (size_t)blockIdx.x * 256 + threadIdx.x;
    float4 a = ((const float4*)out)[i];
    for (int p = 0; p < np; ++p) {
        float4 b = ((const float4*)(parts + (size_t)p * M_TOK * DDIM))[i];
        a.x += b.x; a.y += b.y; a.z += b.z; a.w += b.w;
    }
    ((float4*)out)[i] = a;
}

extern "C" void kernel_launch(void* const* d_in, const int* in_sizes, int n_in,
                              void* d_out, int out_size, void* d_ws, size_t ws_size,
                              hipStream_t stream) {
    (void)in_sizes; (void)n_in; (void)out_size;
    const float* x     = (const float*)d_in[0];
    const float* dec_w = (const float*)d_in[1];
    const float* dec_b = (const float*)d_in[2];
    const float* lw    = (const float*)d_in[3];
    const float* lb    = (const float*)d_in[4];
    float* out = (float*)d_out;
    uint8_t* w8 = (uint8_t*)d_ws;

    unsigned short* xs   = (unsigned short*)(w8);
    unsigned short* wp   = (unsigned short*)(w8 + 75497472);
    float*          bw   = (float*)(w8 + 94371840);
    float*          pmat = (float*)(w8 + 94408704);
    float*          parts= (float*)(w8 + 94539776);
    const size_t NEED3 = 94539776 + 2ull * 16777216;
    const size_t NEED4 = 94539776 + 3ull * 16777216;

    int ks = (ws_size >= NEED4) ? 4 : (ws_size >= NEED3) ? 3 : 0;
    if (!ks) return;

    prep_dec_kernel<<<2048, 256, 0, stream>>>(x, dec_w, dec_b, lw, lb, wp, bw, xs, pmat);

    if (ks == 4) {
        hipError_t e7 = hipFuncSetAttribute(
            reinterpret_cast<const void*>(tree_gemm7),
            hipFuncAttributeMaxDynamicSharedMemorySize, 49152);
        if (e7 == hipSuccess) {
            tree_gemm7<<<512, 512, 49152, stream>>>(xs, wp, out, parts);
            reduce2_kernel<<<4096, 256, 0, stream>>>(out, parts, pmat, bw, 3);
            return;
        }
    }

    hipError_t e5 = hipFuncSetAttribute(
        reinterpret_cast<const void*>(tree_gemm5),
        hipFuncAttributeMaxDynamicSharedMemorySize, 163840);
    if (e5 == hipSuccess) {
        tree_gemm5<<<dim3(64, ks), 512, 163840, stream>>>(xs, wp, out, parts, KFLAT / ks);
        reduce2_kernel<<<4096, 256, 0, stream>>>(out, parts, pmat, bw, ks - 1);
    } else {
        tree_gemm3<<<dim3(256, ks), 256, 0, stream>>>(xs, wp, bw, pmat, out, parts, KFLAT / ks);
        reduce_kernel<<<4096, 256, 0, stream>>>(out, parts, ks - 1);
    }
}

// Round 10
// 123.433 us; speedup vs baseline: 1.1484x; 1.1267x over previous
//
#include <hip/hip_runtime.h>
#include <stdint.h>

// DecisionTree: out = sum_l p_l * (x @ W_l^T + b_l), p from bottom-layer sigmoids.
// Pair-folded + A-prescaled: ONE flat GEMM A[4096x9216] @ B[1024x9216]^T.
// tree_gemm8: gemm5 base (256^2, BK=64, A 2-buf + B 3-buf = 160KB) +
// CROSS-TILE FRAGMENT PIPELINING: mid-tile {lgkm0; vmcnt; barrier}, then next
// tile's 12 ds_reads issue UNDER MFMA_Q(3) (r7-r9 showed LDS and MFMA pipes
// run serialized: wall = LDS 2304 + MFMA 2483 cyc/tile; overlap -> ~max).

#define M_TOK 4096
#define DDIM  1024
#define KFLAT 9216

typedef __bf16 bf16x8 __attribute__((ext_vector_type(8)));
typedef float  f32x4  __attribute__((ext_vector_type(4)));
typedef unsigned short u16x4 __attribute__((ext_vector_type(4)));
typedef unsigned short u16x8 __attribute__((ext_vector_type(8)));

#define GLB(p) ((const __attribute__((address_space(1))) void*)(p))
#define LDS(p) ((__attribute__((address_space(3))) void*)(p))

__device__ __forceinline__ unsigned short f2bf(float f) {
    union { float f; uint32_t u; } v; v.f = f;
    uint32_t u = v.u;
    return (unsigned short)((u + 0x7fffu + ((u >> 16) & 1u)) >> 16);  // RNE
}

__device__ __forceinline__ bf16x8 asbf(f32x4 v) {
    bf16x8 r; __builtin_memcpy(&r, &v, 16); return r;
}

template<int OFF>
__device__ __forceinline__ f32x4 dsr(uint32_t a) {
    f32x4 r;
    asm volatile("ds_read_b128 %0, %1 offset:%c2" : "=v"(r) : "v"(a), "i"(OFF));
    return r;
}

// ---- fused prep: blocks [0,1024) build W'(flat-K) + bias; [1024,2048) build xs + pmat ----
__global__ __launch_bounds__(256) void prep_dec_kernel(
    const float* __restrict__ x, const float* __restrict__ dec_w,
    const float* __restrict__ dec_b, const float* __restrict__ lw,
    const float* __restrict__ lb, unsigned short* __restrict__ wp,
    float* __restrict__ bw, unsigned short* __restrict__ xs,
    float* __restrict__ pmat)
{
    if (blockIdx.x < 1024) {
        int idx = blockIdx.x * 256 + threadIdx.x;     // (o, k4)
        int o  = idx >> 8;
        int k4 = (idx & 255) << 2;
        size_t src = (size_t)o * DDIM + k4;
        size_t dstb = (size_t)o * KFLAT + k4;
        float4 acc = make_float4(0.f, 0.f, 0.f, 0.f);
#pragma unroll
        for (int j = 0; j < 8; ++j) {
            const float4 a = *(const float4*)(lw + (size_t)(2*j)   * DDIM*DDIM + src);
            const float4 b = *(const float4*)(lw + (size_t)(2*j+1) * DDIM*DDIM + src);
            u16x4 d;
            d[0] = f2bf(a.x - b.x); d[1] = f2bf(a.y - b.y);
            d[2] = f2bf(a.z - b.z); d[3] = f2bf(a.w - b.w);
            *(u16x4*)(wp + dstb + (size_t)j * DDIM) = d;
            acc.x += b.x; acc.y += b.y; acc.z += b.z; acc.w += b.w;
        }
        u16x4 s;
        s[0] = f2bf(acc.x); s[1] = f2bf(acc.y); s[2] = f2bf(acc.z); s[3] = f2bf(acc.w);
        *(u16x4*)(wp + dstb + (size_t)8 * DDIM) = s;
        if ((idx & 255) == 0) {
            float sb = 0.f;
#pragma unroll
            for (int j = 0; j < 8; ++j) {
                float ba = lb[(2*j) * DDIM + o];
                float bb = lb[(2*j+1) * DDIM + o];
                bw[j * DDIM + o] = ba - bb;
                sb += bb;
            }
            bw[8 * DDIM + o] = sb;
        }
    } else {
        int m    = (blockIdx.x - 1024) * 4 + (threadIdx.x >> 6);
        int lane = threadIdx.x & 63;
        const float* xr = x + (size_t)m * DDIM + lane * 16;
        float xv[16];
        *(float4*)&xv[0]  = *(const float4*)(xr + 0);
        *(float4*)&xv[4]  = *(const float4*)(xr + 4);
        *(float4*)&xv[8]  = *(const float4*)(xr + 8);
        *(float4*)&xv[12] = *(const float4*)(xr + 12);
        float s[8];
#pragma unroll
        for (int j = 0; j < 8; ++j) {
            const float* wr = dec_w + (size_t)(7 + j) * DDIM + lane * 16;
            float a = 0.f;
#pragma unroll
            for (int i = 0; i < 16; i += 4) {
                float4 wv = *(const float4*)(wr + i);
                a = fmaf(xv[i], wv.x, fmaf(xv[i+1], wv.y, fmaf(xv[i+2], wv.z, fmaf(xv[i+3], wv.w, a))));
            }
            s[j] = a;
        }
#pragma unroll
        for (int j = 0; j < 8; ++j)
#pragma unroll
            for (int off = 32; off > 0; off >>= 1)
                s[j] += __shfl_xor(s[j], off);
        float p[8];
#pragma unroll
        for (int j = 0; j < 8; ++j)
            p[j] = 1.0f / (1.0f + expf(-(s[j] + dec_b[7 + j])));
        if (lane == 0) {
#pragma unroll
            for (int j = 0; j < 8; ++j)
                pmat[(size_t)m * 8 + j] = p[j];
        }
#pragma unroll
        for (int j = 0; j < 9; ++j) {
            float pj = (j < 8) ? p[j] : 1.0f;
            unsigned short* dst = xs + (size_t)m * KFLAT + j * DDIM + lane * 16;
#pragma unroll
            for (int c = 0; c < 2; ++c) {
                u16x8 o;
#pragma unroll
                for (int e = 0; e < 8; ++e) o[e] = f2bf(pj * xv[c * 8 + e]);
                *(u16x8*)(dst + c * 8) = o;
            }
        }
    }
}

// ---- wait macros ----
#define WAITV0 asm volatile("s_waitcnt vmcnt(0)" ::: "memory")
#define WAITV4 asm volatile("s_waitcnt vmcnt(4)" ::: "memory")
#define WAITV8 asm volatile("s_waitcnt vmcnt(8)" ::: "memory")
#define BARR   __builtin_amdgcn_s_barrier()
#define SBAR   __builtin_amdgcn_sched_barrier(0)
#define LGKM0  do { asm volatile("s_waitcnt lgkmcnt(0)" ::: "memory"); SBAR; } while(0)
#define LGKM4  do { asm volatile("s_waitcnt lgkmcnt(4)" ::: "memory"); SBAR; } while(0)

#define MFMA_Q(q, ASET, BSET) do { \
    __builtin_amdgcn_s_setprio(1); \
    _Pragma("unroll") \
    for (int mfl = 0; mfl < 2; ++mfl) { \
        _Pragma("unroll") \
        for (int j = 0; j < 4; ++j) { \
            acc[2*(q)+mfl][j] = __builtin_amdgcn_mfma_f32_16x16x32_bf16(asbf(ASET[mfl][0]), asbf(BSET[j][0]), acc[2*(q)+mfl][j], 0, 0, 0); \
            acc[2*(q)+mfl][j] = __builtin_amdgcn_mfma_f32_16x16x32_bf16(asbf(ASET[mfl][1]), asbf(BSET[j][1]), acc[2*(q)+mfl][j], 0, 0, 0); \
        } \
    } \
    __builtin_amdgcn_s_setprio(0); \
} while(0)

#define READ_A(SET, q, a0, a1) do { \
    SET[0][0] = dsr<(2*(q)+0)*2048>(a0); \
    SET[0][1] = dsr<(2*(q)+0)*2048>(a1); \
    SET[1][0] = dsr<(2*(q)+1)*2048>(a0); \
    SET[1][1] = dsr<(2*(q)+1)*2048>(a1); \
} while(0)

#define READ_B(SET, b0, b1) do { \
    SET[0][0] = dsr<0*2048>(b0); SET[0][1] = dsr<0*2048>(b1); \
    SET[1][0] = dsr<1*2048>(b0); SET[1][1] = dsr<1*2048>(b1); \
    SET[2][0] = dsr<2*2048>(b0); SET[2][1] = dsr<2*2048>(b1); \
    SET[3][0] = dsr<3*2048>(b0); SET[3][1] = dsr<3*2048>(b1); \
} while(0)

// ================= tree_gemm8: fragment-pipelined flowing schedule, 160 KB =================
// LDS: A0@0 A1@32K | B0@64K B1@96K B2@128K. Row = 128B, G4 swizzle byte^=(row&7)<<4.
// Per tile: body Q0-Q2 counted-lgkm; {LGKM0; vmcnt; BARR}; 12 next-tile ds_reads; Q3.
__global__ __launch_bounds__(512, 2) void tree_gemm8(
    const unsigned short* __restrict__ xs, const unsigned short* __restrict__ wp,
    float* __restrict__ out, float* __restrict__ parts, int KG)
{
    extern __shared__ char smem[];
    const int tid  = threadIdx.x;
    const int lane = tid & 63;
    const int w    = tid >> 6;
    const int wm   = w >> 2, wn = w & 3;     // 2M x 4N, wave tile 128x64
    const int ra   = lane & 15;
    const int g16  = lane >> 4;

    const int bx  = blockIdx.x;
    const int xcd = bx & 7, ii = bx >> 3;
    const int nt  = xcd >> 1;
    const int mt  = (xcd & 1) * 8 + ii;
    const int m0  = mt * 256, n0 = nt * 256;
    const int g   = blockIdx.y;
    const int k0  = g * KG;
    const int NT  = KG >> 6;                 // 36 (even)

    uint32_t sbase = (uint32_t)(uintptr_t)(__attribute__((address_space(3))) char*)smem;
    const uint32_t colb0 = (uint32_t)((g16 ^ (ra & 7)) << 4);
    const uint32_t colb1 = colb0 ^ 64;
    const uint32_t baseA0s = sbase + wm * 16384 + ra * 128 + colb0;
    const uint32_t baseA1s = sbase + wm * 16384 + ra * 128 + colb1;
    const uint32_t baseB0s = sbase + 65536 + wn * 8192 + ra * 128 + colb0;
    const uint32_t baseB1s = sbase + 65536 + wn * 8192 + ra * 128 + colb1;

    const int kel = (((lane & 7) ^ (lane >> 3)) & 7) * 8;
    const int rA  = w * 8 + (lane >> 3);

    auto stageA = [&](int buf, int tt, int hh) {
        const unsigned short* s0 = xs + (size_t)(m0 + hh * 128 + rA) * KFLAT + (k0 + tt * 64 + kel);
        char* d0 = smem + buf * 32768 + hh * 16384 + w * 1024;
        __builtin_amdgcn_global_load_lds(GLB(s0), LDS(d0), 16, 0, 0);
        __builtin_amdgcn_global_load_lds(GLB(s0 + (size_t)64 * KFLAT), LDS(d0 + 8192), 16, 0, 0);
    };
    auto stageB = [&](int buf, int tt, int hh) {
        const unsigned short* s0 = wp + (size_t)(n0 + hh * 128 + rA) * KFLAT + (k0 + tt * 64 + kel);
        char* d0 = smem + 65536 + buf * 32768 + hh * 16384 + w * 1024;
        __builtin_amdgcn_global_load_lds(GLB(s0), LDS(d0), 16, 0, 0);
        __builtin_amdgcn_global_load_lds(GLB(s0 + (size_t)64 * KFLAT), LDS(d0 + 8192), 16, 0, 0);
    };

    f32x4 acc[8][4] = {};
    f32x4 avA[2][2], avB[2][2], bvX[4][2], bvY[4][2];

    // prologue: A(0), B(0), B(1) = 12 gloads; vmcnt(4) drains tile-0, keeps B(1).
    stageA(0, 0, 0); stageA(0, 0, 1);
    stageB(0, 0, 0); stageB(0, 0, 1);
    stageB(1, 1, 0); stageB(1, 1, 1);
    WAITV4;
    BARR;
    // preload tile-0 fragments: B(0)->bvX (8) + A(0,q0)->avA (4)
    READ_B(bvX, baseB0s, baseB1s);
    READ_A(avA, 0, baseA0s, baseA1s);

    int bt1 = 1, bt2 = 2;                    // (t+1)%3, (t+2)%3

    // TILE_BODY: CUR = this tile's B frags, NXT = set filled for t+1.
#define TILE_BODY(T, CUR, NXT) do { \
    const int t_ = (T); \
    const bool s1 = (t_ + 1 < NT), s2 = (t_ + 2 < NT); \
    if (s1) { stageA((t_ + 1) & 1, t_ + 1, 0); stageA((t_ + 1) & 1, t_ + 1, 1); } \
    if (s2) { stageB(bt2, t_ + 2, 0); stageB(bt2, t_ + 2, 1); } \
    const uint32_t a0_ = baseA0s + ((uint32_t)(t_ & 1) << 15); \
    const uint32_t a1_ = baseA1s + ((uint32_t)(t_ & 1) << 15); \
    READ_A(avB, 1, a0_, a1_); \
    LGKM4;  MFMA_Q(0, avA, CUR); \
    READ_A(avA, 2, a0_, a1_); \
    LGKM4;  MFMA_Q(1, avB, CUR); \
    READ_A(avB, 3, a0_, a1_); \
    LGKM4;  MFMA_Q(2, avA, CUR); \
    LGKM0; \
    if (s1) { \
        if (s2) { WAITV4; } else { WAITV0; } \
        BARR; \
        const uint32_t nb0_ = baseB0s + (uint32_t)bt1 * 32768u; \
        const uint32_t nb1_ = baseB1s + (uint32_t)bt1 * 32768u; \
        const uint32_t na0_ = baseA0s + ((uint32_t)((t_ + 1) & 1) << 15); \
        const uint32_t na1_ = baseA1s + ((uint32_t)((t_ + 1) & 1) << 15); \
        READ_B(NXT, nb0_, nb1_); \
        READ_A(avA, 0, na0_, na1_); \
    } \
    MFMA_Q(3, avB, CUR); \
    SBAR; \
    bt1 = (bt1 == 2) ? 0 : bt1 + 1; \
    bt2 = (bt2 == 2) ? 0 : bt2 + 1; \
} while(0)

    for (int tp = 0; tp < NT; tp += 2) {
        TILE_BODY(tp,     bvX, bvY);
        TILE_BODY(tp + 1, bvY, bvX);
    }
#undef TILE_BODY

    float* dst = (g == 0) ? out : parts + (size_t)(g - 1) * M_TOK * DDIM;
#pragma unroll
    for (int mf = 0; mf < 8; ++mf)
#pragma unroll
        for (int e = 0; e < 4; ++e) {
            int row = m0 + wm * 128 + mf * 16 + g16 * 4 + e;
#pragma unroll
            for (int j = 0; j < 4; ++j)
                dst[(size_t)row * DDIM + n0 + wn * 64 + j * 16 + ra] = acc[mf][j][e];
        }
}

// ---------------- reduce2: out = out + sum parts + bias(p . bw) ----------------
__global__ __launch_bounds__(256) void reduce2_kernel(
    float* __restrict__ out, const float* __restrict__ parts,
    const float* __restrict__ pmat, const float* __restrict__ bw, int np)
{
    size_t i = (size_t)blockIdx.x * 256 + threadIdx.x;
    int m   = (int)(i >> 8);
    int col = (int)(i & 255) * 4;
    float4 a = ((const float4*)out)[i];
    for (int p = 0; p < np; ++p) {
        float4 b = ((const float4*)(parts + (size_t)p * M_TOK * DDIM))[i];
        a.x += b.x; a.y += b.y; a.z += b.z; a.w += b.w;
    }
    float4 pa = *(const float4*)(pmat + (size_t)m * 8);
    float4 pb = *(const float4*)(pmat + (size_t)m * 8 + 4);
    float4 bias = *(const float4*)(bw + 8 * DDIM + col);
#pragma unroll
    for (int l = 0; l < 8; ++l) {
        float pl = (l < 4) ? ((const float*)&pa)[l] : ((const float*)&pb)[l - 4];
        float4 bl = *(const float4*)(bw + l * DDIM + col);
        bias.x = fmaf(pl, bl.x, bias.x); bias.y = fmaf(pl, bl.y, bias.y);
        bias.z = fmaf(pl, bl.z, bias.z); bias.w = fmaf(pl, bl.w, bias.w);
    }
    a.x += bias.x; a.y += bias.y; a.z += bias.z; a.w += bias.w;
    ((float4*)out)[i] = a;
}

// ================= fallback #1 (round-7 proven): tree_gemm5 =================
#define MFMA_Q5(q, SET) do { \
    __builtin_amdgcn_s_setprio(1); \
    _Pragma("unroll") \
    for (int mfl = 0; mfl < 2; ++mfl) { \
        _Pragma("unroll") \
        for (int j = 0; j < 4; ++j) { \
            acc[2*(q)+mfl][j] = __builtin_amdgcn_mfma_f32_16x16x32_bf16(asbf(SET[mfl][0]), asbf(bv[j][0]), acc[2*(q)+mfl][j], 0, 0, 0); \
            acc[2*(q)+mfl][j] = __builtin_amdgcn_mfma_f32_16x16x32_bf16(asbf(SET[mfl][1]), asbf(bv[j][1]), acc[2*(q)+mfl][j], 0, 0, 0); \
        } \
    } \
    __builtin_amdgcn_s_setprio(0); \
} while(0)

__global__ __launch_bounds__(512, 2) void tree_gemm5(
    const unsigned short* __restrict__ xs, const unsigned short* __restrict__ wp,
    float* __restrict__ out, float* __restrict__ parts, int KG)
{
    extern __shared__ char smem[];
    const int tid  = threadIdx.x;
    const int lane = tid & 63;
    const int w    = tid >> 6;
    const int wm   = w >> 2, wn = w & 3;
    const int ra   = lane & 15;
    const int g16  = lane >> 4;
    const int bx  = blockIdx.x;
    const int xcd = bx & 7, ii = bx >> 3;
    const int nt  = xcd >> 1;
    const int mt  = (xcd & 1) * 8 + ii;
    const int m0  = mt * 256, n0 = nt * 256;
    const int g   = blockIdx.y;
    const int k0  = g * KG;
    const int NT  = KG >> 6;
    uint32_t sbase = (uint32_t)(uintptr_t)(__attribute__((address_space(3))) char*)smem;
    const uint32_t colb0 = (uint32_t)((g16 ^ (ra & 7)) << 4);
    const uint32_t colb1 = colb0 ^ 64;
    const uint32_t baseA0s = sbase + wm * 16384 + ra * 128 + colb0;
    const uint32_t baseA1s = sbase + wm * 16384 + ra * 128 + colb1;
    const uint32_t baseB0s = sbase + 65536 + wn * 8192 + ra * 128 + colb0;
    const uint32_t baseB1s = sbase + 65536 + wn * 8192 + ra * 128 + colb1;
    const int kel = (((lane & 7) ^ (lane >> 3)) & 7) * 8;
    const int rA  = w * 8 + (lane >> 3);
    auto stageA = [&](int buf, int tt, int hh) {
        const unsigned short* s0 = xs + (size_t)(m0 + hh * 128 + rA) * KFLAT + (k0 + tt * 64 + kel);
        char* d0 = smem + buf * 32768 + hh * 16384 + w * 1024;
        __builtin_amdgcn_global_load_lds(GLB(s0), LDS(d0), 16, 0, 0);
        __builtin_amdgcn_global_load_lds(GLB(s0 + (size_t)64 * KFLAT), LDS(d0 + 8192), 16, 0, 0);
    };
    auto stageB = [&](int buf, int tt, int hh) {
        const unsigned short* s0 = wp + (size_t)(n0 + hh * 128 + rA) * KFLAT + (k0 + tt * 64 + kel);
        char* d0 = smem + 65536 + buf * 32768 + hh * 16384 + w * 1024;
        __builtin_amdgcn_global_load_lds(GLB(s0), LDS(d0), 16, 0, 0);
        __builtin_amdgcn_global_load_lds(GLB(s0 + (size_t)64 * KFLAT), LDS(d0 + 8192), 16, 0, 0);
    };
    f32x4 acc[8][4] = {};
    f32x4 avA[2][2], avB[2][2], bv[4][2];
    stageA(0, 0, 0); stageA(0, 0, 1);
    stageB(0, 0, 0); stageB(0, 0, 1);
    stageA(1, 1, 0); stageA(1, 1, 1);
    stageB(1, 1, 0); stageB(1, 1, 1);
    WAITV8; BARR;
    int bt = 0, bt2 = 2;
    for (int t = 0; t < NT; ++t) {
        if (t) {
            if (t == NT - 1) { WAITV0; } else { WAITV4; }
            BARR;
        }
        if (t + 1 < NT) { stageA((t + 1) & 1, t + 1, 0); stageA((t + 1) & 1, t + 1, 1); }
        if (t + 2 < NT) { stageB(bt2, t + 2, 0); stageB(bt2, t + 2, 1); }
        const uint32_t aoff = (uint32_t)(t & 1) << 15;
        const uint32_t boffv = (uint32_t)bt << 15;
        const uint32_t bA0 = baseA0s + aoff, bA1 = baseA1s + aoff;
        const uint32_t bB0 = baseB0s + boffv, bB1 = baseB1s + boffv;
        READ_B(bv, bB0, bB1);
        READ_A(avA, 0, bA0, bA1);
        READ_A(avB, 1, bA0, bA1);
        LGKM4;  MFMA_Q5(0, avA);
        READ_A(avA, 2, bA0, bA1);
        LGKM4;  MFMA_Q5(1, avB);
        READ_A(avB, 3, bA0, bA1);
        LGKM4;  MFMA_Q5(2, avA);
        LGKM0;  MFMA_Q5(3, avB);
        bt  = (bt  == 2) ? 0 : bt  + 1;
        bt2 = (bt2 == 2) ? 0 : bt2 + 1;
    }
    float* dst = (g == 0) ? out : parts + (size_t)(g - 1) * M_TOK * DDIM;
#pragma unroll
    for (int mf = 0; mf < 8; ++mf)
#pragma unroll
        for (int e = 0; e < 4; ++e) {
            int row = m0 + wm * 128 + mf * 16 + g16 * 4 + e;
#pragma unroll
            for (int j = 0; j < 4; ++j)
                dst[(size_t)row * DDIM + n0 + wn * 64 + j * 16 + ra] = acc[mf][j][e];
        }
}

// ================= fallback #2 (round-3 proven): tree_gemm3 + reduce =================
__global__ __launch_bounds__(256, 4) void tree_gemm3(
    const unsigned short* __restrict__ xs, const unsigned short* __restrict__ wp,
    const float* __restrict__ bw, const float* __restrict__ pmat,
    float* __restrict__ out, float* __restrict__ parts, int KG)
{
    __shared__ __align__(16) unsigned short Asm[2][128 * 32];
    __shared__ __align__(16) unsigned short Bsm[2][128 * 32];
    const int tid  = threadIdx.x;
    const int lane = tid & 63;
    const int w    = tid >> 6;
    const int wm   = w >> 1, wn = w & 1;
    const int bx   = blockIdx.x;
    const int xcd  = bx & 7;
    const int ii   = bx >> 3;
    const int mt   = xcd * 4 + (ii >> 3);
    const int nt   = ii & 7;
    const int m0   = mt * 128, n0 = nt * 128;
    const int g    = blockIdx.y;
    const int k0   = g * KG;
    const int ra   = lane & 15;
    const int kb   = (lane >> 4) * 8;
    f32x4 acc[4][4] = {};
    auto stage = [&](int buf, int t) {
#pragma unroll
        for (int c = 0; c < 2; ++c) {
            int row = w * 32 + c * 16 + (lane >> 2);
            int ke  = k0 + t * 32 + (lane & 3) * 8;
            const unsigned short* ga = xs + (size_t)(m0 + row) * KFLAT + ke;
            __builtin_amdgcn_global_load_lds(GLB(ga), LDS(&Asm[buf][w * 1024 + c * 512]), 16, 0, 0);
            const unsigned short* gb = wp + (size_t)(n0 + row) * KFLAT + ke;
            __builtin_amdgcn_global_load_lds(GLB(gb), LDS(&Bsm[buf][w * 1024 + c * 512]), 16, 0, 0);
        }
    };
    const int TOT = KG >> 5;
    stage(0, 0);
    __syncthreads();
    int cur = 0;
    for (int t = 0; t < TOT; ++t) {
        if (t + 1 < TOT) stage(cur ^ 1, t + 1);
        bf16x8 av2[4], bv2[4];
#pragma unroll
        for (int i2 = 0; i2 < 4; ++i2)
            av2[i2] = *(const bf16x8*)&Asm[cur][(wm * 64 + i2 * 16 + ra) * 32 + kb];
#pragma unroll
        for (int j = 0; j < 4; ++j)
            bv2[j] = *(const bf16x8*)&Bsm[cur][(wn * 64 + j * 16 + ra) * 32 + kb];
#pragma unroll
        for (int i2 = 0; i2 < 4; ++i2)
#pragma unroll
            for (int j = 0; j < 4; ++j)
                acc[i2][j] = __builtin_amdgcn_mfma_f32_16x16x32_bf16(av2[i2], bv2[j], acc[i2][j], 0, 0, 0);
        __syncthreads();
        cur ^= 1;
    }
    float* bsm = (float*)&Asm[0][0];
    if (g == 0) {
        for (int idx = tid; idx < 9 * 128; idx += 256)
            bsm[idx] = bw[(idx >> 7) * DDIM + n0 + (idx & 127)];
    }
    __syncthreads();
    float* dst = (g == 0) ? out : parts + (size_t)(g - 1) * M_TOK * DDIM;
#pragma unroll
    for (int i2 = 0; i2 < 4; ++i2)
#pragma unroll
        for (int r = 0; r < 4; ++r) {
            int row = m0 + wm * 64 + i2 * 16 + (lane >> 4) * 4 + r;
            float4 pa, pb;
            if (g == 0) {
                pa = *(const float4*)(pmat + (size_t)row * 8);
                pb = *(const float4*)(pmat + (size_t)row * 8 + 4);
            }
#pragma unroll
            for (int j = 0; j < 4; ++j) {
                int cl = wn * 64 + j * 16 + ra;
                float v = acc[i2][j][r];
                if (g == 0) {
                    v += pa.x * bsm[0 * 128 + cl] + pa.y * bsm[1 * 128 + cl]
                       + pa.z * bsm[2 * 128 + cl] + pa.w * bsm[3 * 128 + cl]
                       + pb.x * bsm[4 * 128 + cl] + pb.y * bsm[5 * 128 + cl]
                       + pb.z * bsm[6 * 128 + cl] + pb.w * bsm[7 * 128 + cl]
                       + bsm[8 * 128 + cl];
                }
                dst[(size_t)row * DDIM + n0 + cl] = v;
            }
        }
}

__global__ __launch_bounds__(256) void reduce_kernel(
    float* __restrict__ out, const float* __restrict__ parts, int np)
{
    size_t i = (size_t)blockIdx.x * 256 + threadIdx.x;
    float4 a = ((const float4*)out)[i];
    for (int p = 0; p < np; ++p) {
        float4 b = ((const float4*)(parts + (size_t)p * M_TOK * DDIM))[i];
        a.x += b.x; a.y += b.y; a.z += b.z; a.w += b.w;
    }
    ((float4*)out)[i] = a;
}

extern "C" void kernel_launch(void* const* d_in, const int* in_sizes, int n_in,
                              void* d_out, int out_size, void* d_ws, size_t ws_size,
                              hipStream_t stream) {
    (void)in_sizes; (void)n_in; (void)out_size;
    const float* x     = (const float*)d_in[0];
    const float* dec_w = (const float*)d_in[1];
    const float* dec_b = (const float*)d_in[2];
    const float* lw    = (const float*)d_in[3];
    const float* lb    = (const float*)d_in[4];
    float* out = (float*)d_out;
    uint8_t* w8 = (uint8_t*)d_ws;

    unsigned short* xs   = (unsigned short*)(w8);
    unsigned short* wp   = (unsigned short*)(w8 + 75497472);
    float*          bw   = (float*)(w8 + 94371840);
    float*          pmat = (float*)(w8 + 94408704);
    float*          parts= (float*)(w8 + 94539776);
    const size_t NEED3 = 94539776 + 2ull * 16777216;
    const size_t NEED4 = 94539776 + 3ull * 16777216;

    int ks = (ws_size >= NEED4) ? 4 : (ws_size >= NEED3) ? 3 : 0;
    if (!ks) return;

    prep_dec_kernel<<<2048, 256, 0, stream>>>(x, dec_w, dec_b, lw, lb, wp, bw, xs, pmat);

    hipError_t e8 = hipFuncSetAttribute(
        reinterpret_cast<const void*>(tree_gemm8),
        hipFuncAttributeMaxDynamicSharedMemorySize, 163840);
    if (e8 == hipSuccess) {
        tree_gemm8<<<dim3(64, ks), 512, 163840, stream>>>(xs, wp, out, parts, KFLAT / ks);
        reduce2_kernel<<<4096, 256, 0, stream>>>(out, parts, pmat, bw, ks - 1);
        return;
    }
    hipError_t e5 = hipFuncSetAttribute(
        reinterpret_cast<const void*>(tree_gemm5),
        hipFuncAttributeMaxDynamicSharedMemorySize, 163840);
    if (e5 == hipSuccess) {
        tree_gemm5<<<dim3(64, ks), 512, 163840, stream>>>(xs, wp, out, parts, KFLAT / ks);
        reduce2_kernel<<<4096, 256, 0, stream>>>(out, parts, pmat, bw, ks - 1);
    } else {
        tree_gemm3<<<dim3(256, ks), 256, 0, stream>>>(xs, wp, bw, pmat, out, parts, KFLAT / ks);
        reduce_kernel<<<4096, 256, 0, stream>>>(out, parts, ks - 1);
    }
}